// Round 9
// baseline (823.077 us; speedup 1.0000x reference)
//
#include <hip/hip_runtime.h>

#define H    2048
#define NH   8
#define NKV  2
#define HD   256
#define DFF  4096
#define PLD  256
#define NL   8
#define WIN  512
#define FULLS 4096
#define EPS  1e-6f
#define ATT_SCALE 0.0625f
#define PLE_PROJ_SCALE 0.022097086912079608f  // 2048^-0.5
#define PLE_IN_SCALE   0.7071067811865476f    // 2^-0.5
#define MS   16
#define NB   1024             // 4 blocks/CU (128 VGPR cap, 14.8KB LDS) -> co-resident
#define NWAVE 4096            // NB*4
#define NGRP 64
#define GSZ  16               // NB/NGRP
#define NSID 56               // 7 barriers per layer * 8 layers

__device__ __forceinline__ float waveSum(float v) {
#pragma unroll
  for (int o = 32; o; o >>= 1) v += __shfl_xor(v, o);
  return v;
}
__device__ __forceinline__ float waveMax(float v) {
#pragma unroll
  for (int o = 32; o; o >>= 1) v = fmaxf(v, __shfl_xor(v, o));
  return v;
}
__device__ __forceinline__ float blockSum(float v) {
  __shared__ float red[4];
  int lane = threadIdx.x & 63, wid = threadIdx.x >> 6;
  v = waveSum(v);
  if (lane == 0) red[wid] = v;
  __syncthreads();
  float s = red[0] + red[1] + red[2] + red[3];
  __syncthreads();
  return s;
}
__device__ __forceinline__ float gelu_t(float x) {
  float x3 = x * x * x;
  return 0.5f * x * (1.f + tanhf(0.79788456080286536f * (x + 0.044715f * x3)));
}

// agent-scope relaxed store -> LLC (coherence point). No dirty L2 lines.
// Safe across replays by value-determinism (validated r5/r6).
__device__ __forceinline__ void ast(float* p, float v) {
  __hip_atomic_store(p, v, __ATOMIC_RELAXED, __HIP_MEMORY_SCOPE_AGENT);
}

__device__ __forceinline__ float dot4(float4 w, float4 x, float acc) {
  return fmaf(w.x, x.x, fmaf(w.y, x.y, fmaf(w.z, x.z, fmaf(w.w, x.w, acc))));
}
template <int C>
__device__ __forceinline__ float dotrow(const float* __restrict__ w,
                                        const float* __restrict__ x, int lane) {
  float acc = 0.f;
#pragma unroll
  for (int c = lane * 4; c < C; c += 256)
    acc = dot4(*(const float4*)(w + c), *(const float4*)(x + c), acc);
  return waveSum(acc);
}
// register prefetch: N float4 per lane covering cols [0, N*256) of row w
template <int NPF>
__device__ __forceinline__ void prefetch_row(const float* __restrict__ w, int lane,
                                             float4* pre) {
#pragma unroll
  for (int k = 0; k < NPF; k++) pre[k] = *(const float4*)(w + lane * 4 + k * 256);
}
template <int NPF>
__device__ __forceinline__ float dot_pre(const float4* pre, const float* __restrict__ x,
                                         int lane) {
  float acc = 0.f;
#pragma unroll
  for (int k = 0; k < NPF; k++)
    acc = dot4(pre[k], *(const float4*)(x + k * 256 + lane * 4), acc);
  return acc;
}
template <int C, int OFS>
__device__ __forceinline__ float dot_rest(const float* __restrict__ w,
                                          const float* __restrict__ x, int lane,
                                          float acc) {
#pragma unroll
  for (int c = OFS + lane * 4; c < C; c += 256)
    acc = dot4(*(const float4*)(w + c), *(const float4*)(x + c), acc);
  return acc;
}

// barrier: relaxed tree arrivals + relaxed polling (no cache maintenance).
// Caller drained its stores with a counted vmcnt, leaving prefetches in flight.
__device__ __forceinline__ void gbar_core(int* cnt, int* top, int* go, int sid) {
  __syncthreads();
  if (threadIdx.x == 0) {
    const int grp = blockIdx.x >> 4;   // /GSZ
    int old = __hip_atomic_fetch_add(cnt + (sid * NGRP + grp) * 32, 1,
                                     __ATOMIC_RELAXED, __HIP_MEMORY_SCOPE_AGENT);
    if (old == GSZ - 1) {
      int o2 = __hip_atomic_fetch_add(top + sid * 32, 1,
                                      __ATOMIC_RELAXED, __HIP_MEMORY_SCOPE_AGENT);
      if (o2 == NGRP - 1) {
        for (int g = 0; g < NGRP; g++)
          __hip_atomic_store(go + g * 32, sid + 1, __ATOMIC_RELAXED,
                             __HIP_MEMORY_SCOPE_AGENT);
      }
    }
    while (__hip_atomic_load(go + grp * 32, __ATOMIC_RELAXED,
                             __HIP_MEMORY_SCOPE_AGENT) <= sid)
      __builtin_amdgcn_s_sleep(1);
  }
  __syncthreads();
}
// NSTR = prefetch loads left in flight; older stores drain (in-order vmcnt).
#define GBAR(NSTR) do { \
  asm volatile("s_waitcnt vmcnt(" NSTR ")" ::: "memory"); \
  gbar_core(p.cnt, p.top, p.go, sid); sid++; \
} while (0)
#define MEMPIN asm volatile("" ::: "memory")

struct MegaP {
  const float *hidden, *mask_full, *um, *plr, *cos_s, *sin_s, *cos_f, *sin_f;
  const float *Ksl, *Vsl, *Kfu, *Vfu;
  const float *Wq, *Wk, *Wv, *Wo, *qnw, *knw, *lin, *lpa, *lpf, *lpff;
  const float *Wg, *Wu, *Wd, *Wpg, *Wpp, *lpl, *lsc, *Wple, *plw;
  float *out, *outKs, *outVs, *outKf, *outVf;
  float *projb, *qkvb, *attnb, *wob, *actb, *dnb, *gatedb, *plb;
  float *hs_new, *hs2, *hs3, *part_o, *part_ml;
  int *cnt, *top, *go, *acnt;
};

__global__ __launch_bounds__(256, 4) void k_mega(MegaP p) {
  const int t = threadIdx.x, lane = t & 63, wid = t >> 6, b = blockIdx.x;
  const int gw = b * 4 + wid;          // 0..4095
  int sid = 0;

  __shared__ __align__(16) float xs[2048];
  __shared__ __align__(16) float s_kr[2][256], s_v[2][256], s_q[256], s_qt[256];
  __shared__ float s_sc[64], s_ml[2];
  __shared__ int s_last;

  float4 preB[8];
  bool hasB = false;

  for (int li = 0; li < NL; li++) {
    const bool isf = (li % 5 == 4);
    const float* cosp = isf ? p.cos_f : p.cos_s;
    const float* sinp = isf ? p.sin_f : p.sin_s;
    float* qkvL = p.qkvb + li * 3072;

    // ===== Stage B: hs_new, xs=rms(hs_new)*w_in, QKV rows (+PLE at li=0) =====
    {
      const bool bActive = (li == 0) || (b < 768);   // block-uniform
      if (bActive) {
        float e[8];
        if (li == 0) {
#pragma unroll
          for (int k = 0; k < 8; k++) e[k] = p.hidden[t + 256 * k];
        } else {
          const float* pl  = p.plb + (li - 1) * 2048;
          const float* wpl = p.lpl + (size_t)(li - 1) * 2048;
          const float* hp  = p.hs3 + (li - 1) * 2048;
          float plv[8]; float ss = 0.f;
#pragma unroll
          for (int k = 0; k < 8; k++) { plv[k] = pl[t + 256 * k]; ss += plv[k] * plv[k]; }
          float r1 = rsqrtf(blockSum(ss) * (1.f / 2048.f) + EPS);
          float sc = p.lsc[li - 1];
#pragma unroll
          for (int k = 0; k < 8; k++) {
            int idx = t + 256 * k;
            e[k] = (hp[idx] + plv[k] * r1 * wpl[idx]) * sc;
          }
        }
        float ss2 = 0.f;
#pragma unroll
        for (int k = 0; k < 8; k++) ss2 += e[k] * e[k];
        float r2 = rsqrtf(blockSum(ss2) * (1.f / 2048.f) + EPS);
        const float* w_in = p.lin + (size_t)li * 2048;
        float* hsN = p.hs_new + li * 2048;
#pragma unroll
        for (int k = 0; k < 8; k++) {
          int idx = t + 256 * k;
          xs[idx] = e[k] * r2 * w_in[idx];
          if (b == 0) ast(hsN + idx, e[k]);
        }
        __syncthreads();
        // one row per wave; extra PLE rows wrap for gw<1024 at li==0
        const int nrows = (li == 0) ? 5120 : 3072;
        for (int row = gw; row < nrows; row += NWAVE) {
          const float* wr; const float* xsrc = xs; float* dst; float sc2 = 1.f;
          if (row < 2048)      { wr = p.Wq + ((size_t)li * 2048 + row) * H; dst = qkvL + row; }
          else if (row < 2560) { wr = p.Wk + ((size_t)li * 512 + (row - 2048)) * H; dst = qkvL + row; }
          else if (row < 3072) { wr = p.Wv + ((size_t)li * 512 + (row - 2560)) * H; dst = qkvL + row; }
          else { wr = p.Wple + (size_t)(row - 3072) * H; xsrc = p.hidden;
                 dst = p.projb + (row - 3072); sc2 = PLE_PROJ_SCALE; }
          float s;
          if (row == gw && hasB) s = waveSum(dot_pre<8>(preB, xsrc, lane));
          else                   s = dotrow<2048>(wr, xsrc, lane);
          if (lane == 0) ast(dst, s * sc2);
        }
      }
    }
    MEMPIN;
    GBAR("0");

    // ===== Stage C: attention tasks + cache-update tasks ====================
    {
      const int S = isf ? FULLS : WIN;
      const int nsp = isf ? 16 : 8;          // attended splits (full: j<1024 only)
      const int natt = NH * nsp;
      const int ncache = isf ? 256 : 32;     // tasks of 4096 float4 each
      const int ntask = natt + ncache;
      const int si = (li < 4) ? li : li - 1;
      const float* Kin = isf ? p.Kfu : p.Ksl + (size_t)si * 2 * WIN * HD;
      const float* Vin = isf ? p.Vfu : p.Vsl + (size_t)si * 2 * WIN * HD;
      float* Ko = isf ? p.outKf : p.outKs + (size_t)si * 2 * WIN * HD;
      float* Vo = isf ? p.outVf : p.outVs + (size_t)si * 2 * WIN * HD;
      float* pO  = p.part_o  + (size_t)li * (NH * MS * 256);
      float* pML = p.part_ml + li * (NH * MS * 2);

      if (b < ntask) {
        for (int c = 0; c < 2; c++) {
          float kvv = qkvL[2048 + c * 256 + t];
          float rk = rsqrtf(blockSum(kvv * kvv) * (1.f / 256.f) + EPS);
          float kn = kvv * rk * p.knw[li * 256 + t];
          s_qt[t] = kn;
          float vv = qkvL[2560 + c * 256 + t];
          float rv = rsqrtf(blockSum(vv * vv) * (1.f / 256.f) + EPS);  // syncs s_qt
          float rot = (t < 128) ? -s_qt[t + 128] : s_qt[t - 128];
          s_kr[c][t] = kn * cosp[t] + rot * sinp[t];
          s_v[c][t] = vv * rv;
          __syncthreads();
        }
        const int task = b;
        if (task < natt) {
          const int h = task / nsp, split = task % nsp, kvh = h >> 2;
          const int j0 = split * 64;
          float qv = qkvL[h * 256 + t];
          float rq = rsqrtf(blockSum(qv * qv) * (1.f / 256.f) + EPS);
          float qn = qv * rq * p.qnw[li * 256 + t];
          s_qt[t] = qn;
          __syncthreads();
          float rot = (t < 128) ? -s_qt[t + 128] : s_qt[t - 128];
          s_q[t] = qn * cosp[t] + rot * sinp[t];
          __syncthreads();
          float4 q4 = ((const float4*)s_q)[lane];
          for (int jl = wid; jl < 64; jl += 4) {
            int j = j0 + jl;
            float4 k4;
            if (!isf) {
              k4 = (j < S - 1) ? ((const float4*)Kin)[((size_t)kvh * S + j + 1) * 64 + lane]
                               : ((const float4*)s_kr[kvh])[lane];
            } else {
              k4 = ((const float4*)Kin)[((size_t)kvh * S + j) * 64 + lane];
              float u = p.um[j];
              if (u != 0.f) {
                float om = 1.f - u;
                float4 nk = ((const float4*)s_kr[kvh])[lane];
                k4.x = k4.x * om + nk.x * u; k4.y = k4.y * om + nk.y * u;
                k4.z = k4.z * om + nk.z * u; k4.w = k4.w * om + nk.w * u;
              }
            }
            float pp = q4.x * k4.x + q4.y * k4.y + q4.z * k4.z + q4.w * k4.w;
            pp = waveSum(pp);
            if (lane == 0) s_sc[jl] = pp * ATT_SCALE + (isf ? p.mask_full[j] : 0.f);
          }
          __syncthreads();
          if (wid == 0) {
            float v = s_sc[lane];
            float m = waveMax(v);
            float e = expf(v - m);
            s_sc[lane] = e;
            float l = waveSum(e);
            if (lane == 0) { s_ml[0] = m; s_ml[1] = l; }
          }
          __syncthreads();
          float o = 0.f;
#pragma unroll 8
          for (int jl = 0; jl < 64; jl++) {
            int j = j0 + jl;
            float vj;
            if (!isf) {
              vj = (j < S - 1) ? Vin[((size_t)kvh * S + j + 1) * 256 + t] : s_v[kvh][t];
            } else {
              vj = Vin[((size_t)kvh * S + j) * 256 + t];
              float u = p.um[j];
              if (u != 0.f) vj = vj * (1.f - u) + s_v[kvh][t] * u;
            }
            o = fmaf(s_sc[jl], vj, o);
          }
          ast(pO + ((size_t)h * MS + split) * 256 + t, o);
          if (t < 2) ast(pML + (h * MS + split) * 2 + t, s_ml[t]);
          asm volatile("s_waitcnt vmcnt(0)" ::: "memory");
          __syncthreads();
          if (t == 0) {
            int old = __hip_atomic_fetch_add(p.acnt + li * NH + h, 1,
                                             __ATOMIC_RELAXED, __HIP_MEMORY_SCOPE_AGENT);
            s_last = (old == nsp - 1);
          }
          __syncthreads();
          if (s_last) {
            float M = -INFINITY;
            for (int s2 = 0; s2 < nsp; s2++) M = fmaxf(M, pML[(h * MS + s2) * 2]);
            float L = 0.f, oo = 0.f;
            for (int s2 = 0; s2 < nsp; s2++) {
              float m = pML[(h * MS + s2) * 2];
              float l = pML[(h * MS + s2) * 2 + 1];
              float f = expf(m - M);
              L += l * f;
              oo = fmaf(pO[((size_t)h * MS + s2) * 256 + t], f, oo);
            }
            ast(p.attnb + li * 2048 + h * 256 + t, oo / L);
          }
        } else {
          int ci = task - natt;
          const int fK = 2 * S * 64;
          const float4* Ki4 = (const float4*)Kin;
          const float4* Vi4 = (const float4*)Vin;
          float4* Ko4 = (float4*)Ko;
          float4* Vo4 = (float4*)Vo;
#pragma unroll
          for (int k = 0; k < 16; k++) {
            int idx = ci * 4096 + k * 256 + t;
            int isV = idx >= fK;
            int rid = isV ? idx - fK : idx;
            int kvh = rid / (S * 64);
            int rem = rid % (S * 64);
            int j = rem >> 6, d4 = rem & 63;
            const float4* in4 = isV ? Vi4 : Ki4;
            const float4* nn4 = (const float4*)(isV ? s_v[kvh] : s_kr[kvh]);
            float4 v;
            if (!isf) {
              v = (j < S - 1) ? in4[((size_t)kvh * S + j + 1) * 64 + d4] : nn4[d4];
            } else {
              v = in4[rid];
              float u = p.um[j];
              if (u != 0.f) {
                float om = 1.f - u;
                float4 nv = nn4[d4];
                v.x = v.x * om + nv.x * u; v.y = v.y * om + nv.y * u;
                v.z = v.z * om + nv.z * u; v.w = v.w * om + nv.w * u;
              }
            }
            (isV ? Vo4 : Ko4)[rid] = v;
          }
        }
      }
    }
    MEMPIN;
    // half-row of Wo for stage D (4KB, fully covered)
    float4 preD[4];
    prefetch_row<4>(p.Wo + ((size_t)li * 2048 + (gw >> 1)) * H + (gw & 1) * 1024,
                    lane, preD);
    GBAR("4");

    // ===== Stage D: Wo GEMV as 4096 half-rows (one per wave) ================
    {
      int r = gw >> 1, half = gw & 1;
      float s = waveSum(dot_pre<4>(preD, p.attnb + li * 2048 + half * 1024, lane));
      if (lane == 0) ast(p.wob + li * 4096 + half * 2048 + r, s);
    }
    MEMPIN;
    float4 preG4[4], preU4[4];
    prefetch_row<4>(p.Wg + ((size_t)li * 4096 + gw) * H, lane, preG4);
    prefetch_row<4>(p.Wu + ((size_t)li * 4096 + gw) * H, lane, preU4);
    GBAR("8");

    // ===== Stage E: hs2, xs=rms(hs2)*w_pf, gate/up row gw (one row/wave) ====
    {
      const float* hsN = p.hs_new + li * 2048;
      const float* wo = p.wob + li * 4096;
      const float* w_pa = p.lpa + (size_t)li * 2048;
      const float* w_pf = p.lpf + (size_t)li * 2048;
      float wv[8]; float ss = 0.f;
#pragma unroll
      for (int k = 0; k < 8; k++) {
        int idx = t + 256 * k;
        wv[k] = wo[idx] + wo[2048 + idx];          // sum the two half-row partials
        ss += wv[k] * wv[k];
      }
      float r1 = rsqrtf(blockSum(ss) * (1.f / 2048.f) + EPS);
      float e[8]; float ss2 = 0.f;
#pragma unroll
      for (int k = 0; k < 8; k++) {
        int idx = t + 256 * k;
        e[k] = hsN[idx] + wv[k] * r1 * w_pa[idx];
        ss2 += e[k] * e[k];
      }
      float r2 = rsqrtf(blockSum(ss2) * (1.f / 2048.f) + EPS);
      float* hs2L = p.hs2 + li * 2048;
#pragma unroll
      for (int k = 0; k < 8; k++) {
        int idx = t + 256 * k;
        xs[idx] = e[k] * r2 * w_pf[idx];
        if (b == 0) ast(hs2L + idx, e[k]);
      }
      __syncthreads();
      const float* g = p.Wg + ((size_t)li * 4096 + gw) * H;
      const float* u = p.Wu + ((size_t)li * 4096 + gw) * H;
      float ag = waveSum(dot_rest<2048, 1024>(g, xs, lane, dot_pre<4>(preG4, xs, lane)));
      float au = waveSum(dot_rest<2048, 1024>(u, xs, lane, dot_pre<4>(preU4, xs, lane)));
      if (lane == 0) ast(p.actb + li * 4096 + gw, gelu_t(ag) * au);
    }
    MEMPIN;
    // half-row of Wd (8KB, fully covered)
    float4 preF[8];
    prefetch_row<8>(p.Wd + ((size_t)li * 2048 + (gw >> 1)) * DFF + (gw & 1) * 2048,
                    lane, preF);
    GBAR("8");

    // ===== Stage F: Wd GEMV as 4096 half-rows (one per wave) ================
    {
      int r = gw >> 1, half = gw & 1;
      float s = waveSum(dot_pre<8>(preF, p.actb + li * 4096 + half * 2048, lane));
      if (lane == 0) ast(p.dnb + li * 4096 + half * 2048 + r, s);
    }
    MEMPIN;
    // F->G barrier: only the 64 G-blocks prefetch; everyone else fully drains
    if (b < 64) {
      float4 preP[8];
      prefetch_row<8>(p.Wpg + ((size_t)li * 256 + gw) * H, lane, preP);
      GBAR("8");

      // ===== Stage G: hs3, sl, pl-gate GEMV (256 rows, blocks 0..63) ========
      const float* hs2L = p.hs2 + li * 2048;
      const float* dn = p.dnb + li * 4096;
      const float* w_pff = p.lpff + (size_t)li * 2048;
      float dv[8]; float ss = 0.f;
#pragma unroll
      for (int k = 0; k < 8; k++) {
        int idx = t + 256 * k;
        dv[k] = dn[idx] + dn[2048 + idx];
        ss += dv[k] * dv[k];
      }
      float r1 = rsqrtf(blockSum(ss) * (1.f / 2048.f) + EPS);
      float* hs3L = p.hs3 + li * 2048;
#pragma unroll
      for (int k = 0; k < 8; k++) {
        int idx = t + 256 * k;
        float e = hs2L[idx] + dv[k] * r1 * w_pff[idx];
        xs[idx] = e;
        if (b == 0) ast(hs3L + idx, e);
      }
      float pv = p.projb[li * 256 + t];
      float rp = rsqrtf(blockSum(pv * pv) * (1.f / 256.f) + EPS);
      s_qt[t] = (pv * rp * p.plw[t] + p.plr[li * 256 + t]) * PLE_IN_SCALE;
      __syncthreads();
      float acc = waveSum(dot_pre<8>(preP, xs, lane));
      if (lane == 0) ast(p.gatedb + li * 256 + gw, gelu_t(acc) * s_qt[gw]);
    } else {
      GBAR("0");
      // non-G blocks idle through stage G
    }
    MEMPIN;
    float4 preH;
    if (gw < 2048)
      preH = *(const float4*)(p.Wpp + ((size_t)li * 2048 + gw) * PLD + lane * 4);
    GBAR("1");   // safe for all: G-blocks drain gated store (queue [store,load])

    // ===== Stage H: Wpp GEMV (2048 rows x 256, one row/wave for gw<2048) ====
    if (gw < 2048) {
      float4 x4 = *(const float4*)(p.gatedb + li * 256 + lane * 4);
      float s = waveSum(dot4(preH, x4, 0.f));
      if (lane == 0) ast(p.plb + li * 2048 + gw, s);
    }
    MEMPIN;
    hasB = (li + 1 < NL) && (gw < 3072);
    if (hasB) {
      const float* wr;
      if (gw < 2048)      wr = p.Wq + ((size_t)(li + 1) * 2048 + gw) * H;
      else if (gw < 2560) wr = p.Wk + ((size_t)(li + 1) * 512 + (gw - 2048)) * H;
      else                wr = p.Wv + ((size_t)(li + 1) * 512 + (gw - 2560)) * H;
      prefetch_row<8>(wr, lane, preB);
    }
    GBAR("8");   // drains H store (issued before the 8 prefetches)
  }

  // ===== final: out = (hs3 + rms(pl)*w_pl) * lsc[7] =========================
  if (b == 0) {
    const float* pl = p.plb + 7 * 2048;
    const float* wpl = p.lpl + (size_t)7 * 2048;
    const float* hs3L = p.hs3 + 7 * 2048;
    float pv[8]; float ss = 0.f;
#pragma unroll
    for (int k = 0; k < 8; k++) { pv[k] = pl[t + 256 * k]; ss += pv[k] * pv[k]; }
    float r = rsqrtf(blockSum(ss) * (1.f / 2048.f) + EPS);
    float sc = p.lsc[NL - 1];
#pragma unroll
    for (int k = 0; k < 8; k++) {
      int idx = t + 256 * k;
      p.out[idx] = (hs3L[idx] + pv[k] * r * wpl[idx]) * sc;
    }
  }
}

extern "C" void kernel_launch(void* const* d_in, const int* in_sizes, int n_in,
                              void* d_out, int out_size, void* d_ws, size_t ws_size,
                              hipStream_t stream) {
  MegaP p;
  p.hidden     = (const float*)d_in[0];
  p.mask_full  = (const float*)d_in[1];
  p.um         = (const float*)d_in[3];
  p.plr        = (const float*)d_in[4];
  p.cos_s      = (const float*)d_in[5];
  p.sin_s      = (const float*)d_in[6];
  p.cos_f      = (const float*)d_in[7];
  p.sin_f      = (const float*)d_in[8];
  p.Ksl        = (const float*)d_in[9];
  p.Vsl        = (const float*)d_in[10];
  p.Kfu        = (const float*)d_in[11];
  p.Vfu        = (const float*)d_in[12];
  p.Wq         = (const float*)d_in[13];
  p.Wk         = (const float*)d_in[14];
  p.Wv         = (const float*)d_in[15];
  p.Wo         = (const float*)d_in[16];
  p.qnw        = (const float*)d_in[17];
  p.knw        = (const float*)d_in[18];
  p.lin        = (const float*)d_in[19];
  p.lpa        = (const float*)d_in[20];
  p.lpf        = (const float*)d_in[21];
  p.lpff       = (const float*)d_in[22];
  p.Wg         = (const float*)d_in[23];
  p.Wu         = (const float*)d_in[24];
  p.Wd         = (const float*)d_in[25];
  p.Wpg        = (const float*)d_in[26];
  p.Wpp        = (const float*)d_in[27];
  p.lpl        = (const float*)d_in[28];
  p.lsc        = (const float*)d_in[29];
  p.Wple       = (const float*)d_in[30];
  p.plw        = (const float*)d_in[31];

  float* out = (float*)d_out;
  const size_t KS_SZ = (size_t)7 * 2 * WIN * HD;
  const size_t KF_SZ = (size_t)2 * FULLS * HD;
  p.out   = out;
  p.outKs = out + 2048;
  p.outVs = p.outKs + KS_SZ;
  p.outKf = p.outVs + KS_SZ;
  p.outVf = p.outKf + KF_SZ;

  // ---- workspace: [zeroed int region | float buffers] ----
  int* zi = (int*)d_ws;
  p.cnt  = zi;                                   // 56*64 lines x32 = 114688
  p.top  = zi + 114688;                          // 56 x32 = 1792
  p.go   = zi + 114688 + 1792;                   // 64 x32 = 2048
  p.acnt = zi + 114688 + 1792 + 2048;            // 64
  const size_t ZINTS = 114688 + 1792 + 2048 + 64;  // 118592

  float* f = (float*)d_ws + ZINTS;
  p.projb  = f;  f += 2048;
  p.qkvb   = f;  f += NL * 3072;
  p.attnb  = f;  f += NL * 2048;
  p.wob    = f;  f += NL * 4096;   // [half][2048] per layer
  p.actb   = f;  f += NL * 4096;
  p.dnb    = f;  f += NL * 4096;   // [half][2048] per layer
  p.gatedb = f;  f += NL * 256;
  p.plb    = f;  f += NL * 2048;
  p.hs_new = f;  f += NL * 2048;
  p.hs2    = f;  f += NL * 2048;
  p.hs3    = f;  f += NL * 2048;
  p.part_o = f;  f += (size_t)NL * NH * MS * 256;
  p.part_ml= f;  f += NL * NH * MS * 2;

  (void)hipMemsetAsync(d_ws, 0, ZINTS * sizeof(int), stream);
  k_mega<<<NB, 256, 0, stream>>>(p);
}